// Round 2
// baseline (62.445 us; speedup 1.0000x reference)
//
#include <hip/hip_runtime.h>
#include <hip/hip_bf16.h>

// MultiEmbedding: out1[r,:] = sum_{l<8} W[l, x1[r,l], :]
//                 out2[r,:] = sum_{l<4} W[l, x2[r,l], :]
// W: [8, 1024, 1024] fp32, x1: [8192,8] i32, x2: [8192,4] i32.
// d_out = out1 (8192*1024) then out2 (8192*1024), fp32.

#define TOKEN_DIM 1024
#define N_TOKENS  1024

typedef float f32x4 __attribute__((ext_vector_type(4)));

__global__ __launch_bounds__(256) void multi_embed_kernel(
    const int* __restrict__ x1, const int* __restrict__ x2,
    const float* __restrict__ weight, float* __restrict__ out,
    int n1, int n2)
{
    const int row = blockIdx.x;
    const int c4  = threadIdx.x;            // float4 column index, 256*4 = 1024 cols

    f32x4 acc = (f32x4)(0.f);

    if (row < n1) {
        const int* idx = x1 + (size_t)row * 8;   // uniform across block -> s_load
        #pragma unroll
        for (int l = 0; l < 8; ++l) {
            const int t = idx[l];
            const f32x4* w = reinterpret_cast<const f32x4*>(
                weight + ((size_t)l * N_TOKENS + (size_t)t) * TOKEN_DIM);
            acc += w[c4];
        }
        f32x4* o = reinterpret_cast<f32x4*>(out + (size_t)row * TOKEN_DIM);
        __builtin_nontemporal_store(acc, &o[c4]);
    } else {
        const int r = row - n1;
        if (r >= n2) return;
        const int* idx = x2 + (size_t)r * 4;
        #pragma unroll
        for (int l = 0; l < 4; ++l) {
            const int t = idx[l];
            const f32x4* w = reinterpret_cast<const f32x4*>(
                weight + ((size_t)l * N_TOKENS + (size_t)t) * TOKEN_DIM);
            acc += w[c4];
        }
        f32x4* o = reinterpret_cast<f32x4*>(
            out + ((size_t)n1 + (size_t)r) * TOKEN_DIM);
        __builtin_nontemporal_store(acc, &o[c4]);
    }
}

extern "C" void kernel_launch(void* const* d_in, const int* in_sizes, int n_in,
                              void* d_out, int out_size, void* d_ws, size_t ws_size,
                              hipStream_t stream) {
    const int*   x1 = (const int*)d_in[0];
    const int*   x2 = (const int*)d_in[1];
    const float* w  = (const float*)d_in[2];
    float*       o  = (float*)d_out;

    const int n1 = in_sizes[0] / 8;   // 8192
    const int n2 = in_sizes[1] / 4;   // 8192

    const int blocks = n1 + n2;       // one block per output row
    multi_embed_kernel<<<blocks, 256, 0, stream>>>(x1, x2, w, o, n1, n2);
}

// Round 3
// 47.717 us; speedup vs baseline: 1.3087x; 1.3087x over previous
//
#include <hip/hip_runtime.h>
#include <hip/hip_bf16.h>

// MultiEmbedding: out1[r,:] = sum_{l<8} W[l, x1[r,l], :]
//                 out2[r,:] = sum_{l<4} W[l, x2[r,l], :]
// W: [8, 1024, 1024] fp32, x1: [8192,8] i32, x2: [8192,4] i32.
// Strategy: W -> bf16 in d_ws (16 MiB) once per launch, then gather bf16
// rows (half the read traffic, better L2/L3 residency), accumulate fp32.

#define TOKEN_DIM 1024
#define N_TOKENS  1024
#define N_LEVELS  8

typedef float          f32x4 __attribute__((ext_vector_type(4)));
typedef unsigned short u16x4 __attribute__((ext_vector_type(4)));
typedef unsigned short u16x8 __attribute__((ext_vector_type(8)));

__device__ __forceinline__ unsigned short f2bf_rne(float f) {
    unsigned int u = __float_as_uint(f);
    u += 0x7fffu + ((u >> 16) & 1u);     // round-to-nearest-even
    return (unsigned short)(u >> 16);
}
__device__ __forceinline__ float bf2f(unsigned short u) {
    return __uint_as_float(((unsigned int)u) << 16);
}

// ---- pass 1: fp32 -> bf16 conversion of the weight table ----
__global__ __launch_bounds__(256) void convert_w_kernel(
    const float* __restrict__ w, unsigned short* __restrict__ wb, int n4)
{
    int i = blockIdx.x * 256 + threadIdx.x;
    const int stride = gridDim.x * 256;
    for (; i < n4; i += stride) {
        f32x4 v = reinterpret_cast<const f32x4*>(w)[i];
        u16x4 o;
        o.x = f2bf_rne(v.x); o.y = f2bf_rne(v.y);
        o.z = f2bf_rne(v.z); o.w = f2bf_rne(v.w);
        __builtin_nontemporal_store(o, &reinterpret_cast<u16x4*>(wb)[i]);
    }
}

// ---- pass 2: gather bf16 rows, accumulate fp32 ----
// One 128-thread block per output row; thread t owns cols [8t, 8t+8).
__global__ __launch_bounds__(128) void gather_bf16_kernel(
    const int* __restrict__ x1, const int* __restrict__ x2,
    const unsigned short* __restrict__ wb, float* __restrict__ out,
    int n1, int n2)
{
    const int row = blockIdx.x;
    const int t   = threadIdx.x;

    float acc[8];
    #pragma unroll
    for (int j = 0; j < 8; ++j) acc[j] = 0.f;

    if (row < n1) {
        const int* idx = x1 + (size_t)row * 8;   // block-uniform -> s_load
        u16x8 v[8];
        #pragma unroll
        for (int l = 0; l < 8; ++l) {            // issue all 8 loads first
            const int tok = idx[l];
            v[l] = reinterpret_cast<const u16x8*>(
                wb + ((size_t)l * N_TOKENS + (size_t)tok) * TOKEN_DIM)[t];
        }
        #pragma unroll
        for (int l = 0; l < 8; ++l)
            #pragma unroll
            for (int j = 0; j < 8; ++j) acc[j] += bf2f(v[l][j]);
    } else {
        const int r = row - n1;
        if (r >= n2) return;
        const int* idx = x2 + (size_t)r * 4;
        u16x8 v[4];
        #pragma unroll
        for (int l = 0; l < 4; ++l) {
            const int tok = idx[l];
            v[l] = reinterpret_cast<const u16x8*>(
                wb + ((size_t)l * N_TOKENS + (size_t)tok) * TOKEN_DIM)[t];
        }
        #pragma unroll
        for (int l = 0; l < 4; ++l)
            #pragma unroll
            for (int j = 0; j < 8; ++j) acc[j] += bf2f(v[l][j]);
    }

    f32x4 lo = { acc[0], acc[1], acc[2], acc[3] };
    f32x4 hi = { acc[4], acc[5], acc[6], acc[7] };
    float* obase = out + (size_t)row * TOKEN_DIM + (size_t)t * 8;
    __builtin_nontemporal_store(lo, reinterpret_cast<f32x4*>(obase));
    __builtin_nontemporal_store(hi, reinterpret_cast<f32x4*>(obase) + 1);
}

// ---- fallback: pure fp32 gather (if d_ws too small) ----
__global__ __launch_bounds__(256) void multi_embed_f32_kernel(
    const int* __restrict__ x1, const int* __restrict__ x2,
    const float* __restrict__ weight, float* __restrict__ out,
    int n1, int n2)
{
    const int row = blockIdx.x;
    const int c4  = threadIdx.x;
    f32x4 acc = (f32x4)(0.f);
    if (row < n1) {
        const int* idx = x1 + (size_t)row * 8;
        #pragma unroll
        for (int l = 0; l < 8; ++l) {
            const int tok = idx[l];
            acc += reinterpret_cast<const f32x4*>(
                weight + ((size_t)l * N_TOKENS + (size_t)tok) * TOKEN_DIM)[c4];
        }
    } else {
        const int r = row - n1;
        if (r >= n2) return;
        const int* idx = x2 + (size_t)r * 4;
        #pragma unroll
        for (int l = 0; l < 4; ++l) {
            const int tok = idx[l];
            acc += reinterpret_cast<const f32x4*>(
                weight + ((size_t)l * N_TOKENS + (size_t)tok) * TOKEN_DIM)[c4];
        }
    }
    f32x4* o = reinterpret_cast<f32x4*>(out + (size_t)row * TOKEN_DIM);
    __builtin_nontemporal_store(acc, &o[c4]);
}

extern "C" void kernel_launch(void* const* d_in, const int* in_sizes, int n_in,
                              void* d_out, int out_size, void* d_ws, size_t ws_size,
                              hipStream_t stream) {
    const int*   x1 = (const int*)d_in[0];
    const int*   x2 = (const int*)d_in[1];
    const float* w  = (const float*)d_in[2];
    float*       o  = (float*)d_out;

    const int n1 = in_sizes[0] / 8;   // 8192
    const int n2 = in_sizes[1] / 4;   // 8192

    const size_t wb_bytes = (size_t)N_LEVELS * N_TOKENS * TOKEN_DIM * sizeof(unsigned short);

    if (ws_size >= wb_bytes) {
        unsigned short* wb = (unsigned short*)d_ws;
        const int n4 = (N_LEVELS * N_TOKENS * TOKEN_DIM) / 4;   // 2M float4s
        convert_w_kernel<<<2048, 256, 0, stream>>>(w, wb, n4);
        gather_bf16_kernel<<<n1 + n2, 128, 0, stream>>>(x1, x2, wb, o, n1, n2);
    } else {
        multi_embed_f32_kernel<<<n1 + n2, 256, 0, stream>>>(x1, x2, w, o, n1, n2);
    }
}

// Round 4
// 39.282 us; speedup vs baseline: 1.5897x; 1.2147x over previous
//
#include <hip/hip_runtime.h>
#include <hip/hip_bf16.h>

// MultiEmbedding: out1[r,:] = sum_{l<8} W[l, x1[r,l], :]
//                 out2[r,:] = sum_{l<4} W[l, x2[r,l], :]
// W: [8, 1024, 1024] fp32, x1: [8192,8] i32, x2: [8192,4] i32.
//
// Pass 1: W -> bf16 in d_ws (16 MiB).
// Pass 2: column-sliced gather. Slice s = blockIdx.x & 7 -> XCD s (round-robin
// dispatch), so each XCD's weight working set is 16 MiB / 8 = 2 MiB, resident
// in its 4 MiB private L2. Gather reads then hit L2 instead of L3/HBM.

#define TOKEN_DIM 1024
#define N_TOKENS  1024
#define N_LEVELS  8

#define COLS_PER_SLICE 128   // TOKEN_DIM / 8 slices
#define ROWS_PER_BLOCK 64
#define ROWS_PER_ITER  16    // 256 threads / 16 col-groups

typedef float          f32x4 __attribute__((ext_vector_type(4)));
typedef unsigned short u16x4 __attribute__((ext_vector_type(4)));
typedef unsigned short u16x8 __attribute__((ext_vector_type(8)));

__device__ __forceinline__ unsigned short f2bf_rne(float f) {
    unsigned int u = __float_as_uint(f);
    u += 0x7fffu + ((u >> 16) & 1u);     // round-to-nearest-even
    return (unsigned short)(u >> 16);
}
__device__ __forceinline__ float bf2f(unsigned short u) {
    return __uint_as_float(((unsigned int)u) << 16);
}

// ---- pass 1: fp32 -> bf16 conversion of the weight table ----
__global__ __launch_bounds__(256) void convert_w_kernel(
    const float* __restrict__ w, unsigned short* __restrict__ wb, int n4)
{
    int i = blockIdx.x * 256 + threadIdx.x;
    const int stride = gridDim.x * 256;
    for (; i < n4; i += stride) {
        f32x4 v = reinterpret_cast<const f32x4*>(w)[i];
        u16x4 o;
        o.x = f2bf_rne(v.x); o.y = f2bf_rne(v.y);
        o.z = f2bf_rne(v.z); o.w = f2bf_rne(v.w);
        __builtin_nontemporal_store(o, &reinterpret_cast<u16x4*>(wb)[i]);
    }
}

// ---- pass 2: column-sliced gather ----
// blockIdx.x = chunk*8 + slice. Thread t: col-group g = t&15 (8 cols each),
// local row lr = t>>4 (16 rows per iteration).
__global__ __launch_bounds__(256) void gather_sliced_kernel(
    const int* __restrict__ x1, const int* __restrict__ x2,
    const unsigned short* __restrict__ wb, float* __restrict__ out,
    int n1, int n2)
{
    const int slice = blockIdx.x & 7;
    const int chunk = blockIdx.x >> 3;
    const int row0  = chunk * ROWS_PER_BLOCK;
    const int g     = threadIdx.x & 15;
    const int lr    = threadIdx.x >> 4;
    const int col   = slice * COLS_PER_SLICE + g * 8;

    const bool is_x1 = (row0 < n1);   // chunks never straddle (n1 % 64 == 0)

    #pragma unroll
    for (int it = 0; it < ROWS_PER_BLOCK / ROWS_PER_ITER; ++it) {
        const int row = row0 + it * ROWS_PER_ITER + lr;

        float acc[8];
        #pragma unroll
        for (int j = 0; j < 8; ++j) acc[j] = 0.f;

        if (is_x1) {
            const int* idx = x1 + (size_t)row * 8;
            u16x8 v[8];
            #pragma unroll
            for (int l = 0; l < 8; ++l) {
                const int tok = idx[l];
                v[l] = *reinterpret_cast<const u16x8*>(
                    wb + ((size_t)l * N_TOKENS + (size_t)tok) * TOKEN_DIM + col);
            }
            #pragma unroll
            for (int l = 0; l < 8; ++l)
                #pragma unroll
                for (int j = 0; j < 8; ++j) acc[j] += bf2f(v[l][j]);
        } else {
            const int r = row - n1;
            const int* idx = x2 + (size_t)r * 4;
            u16x8 v[4];
            #pragma unroll
            for (int l = 0; l < 4; ++l) {
                const int tok = idx[l];
                v[l] = *reinterpret_cast<const u16x8*>(
                    wb + ((size_t)l * N_TOKENS + (size_t)tok) * TOKEN_DIM + col);
            }
            #pragma unroll
            for (int l = 0; l < 4; ++l)
                #pragma unroll
                for (int j = 0; j < 8; ++j) acc[j] += bf2f(v[l][j]);
        }

        f32x4 lo = { acc[0], acc[1], acc[2], acc[3] };
        f32x4 hi = { acc[4], acc[5], acc[6], acc[7] };
        float* obase = out + (size_t)row * TOKEN_DIM + col;
        __builtin_nontemporal_store(lo, reinterpret_cast<f32x4*>(obase));
        __builtin_nontemporal_store(hi, reinterpret_cast<f32x4*>(obase) + 1);
    }
}

// ---- fallback: per-row bf16 gather (shapes not divisible) ----
__global__ __launch_bounds__(128) void gather_bf16_kernel(
    const int* __restrict__ x1, const int* __restrict__ x2,
    const unsigned short* __restrict__ wb, float* __restrict__ out,
    int n1, int n2)
{
    const int row = blockIdx.x;
    const int t   = threadIdx.x;
    float acc[8];
    #pragma unroll
    for (int j = 0; j < 8; ++j) acc[j] = 0.f;

    if (row < n1) {
        const int* idx = x1 + (size_t)row * 8;
        u16x8 v[8];
        #pragma unroll
        for (int l = 0; l < 8; ++l) {
            const int tok = idx[l];
            v[l] = reinterpret_cast<const u16x8*>(
                wb + ((size_t)l * N_TOKENS + (size_t)tok) * TOKEN_DIM)[t];
        }
        #pragma unroll
        for (int l = 0; l < 8; ++l)
            #pragma unroll
            for (int j = 0; j < 8; ++j) acc[j] += bf2f(v[l][j]);
    } else {
        const int r = row - n1;
        if (r >= n2) return;
        const int* idx = x2 + (size_t)r * 4;
        u16x8 v[4];
        #pragma unroll
        for (int l = 0; l < 4; ++l) {
            const int tok = idx[l];
            v[l] = reinterpret_cast<const u16x8*>(
                wb + ((size_t)l * N_TOKENS + (size_t)tok) * TOKEN_DIM)[t];
        }
        #pragma unroll
        for (int l = 0; l < 4; ++l)
            #pragma unroll
            for (int j = 0; j < 8; ++j) acc[j] += bf2f(v[l][j]);
    }

    f32x4 lo = { acc[0], acc[1], acc[2], acc[3] };
    f32x4 hi = { acc[4], acc[5], acc[6], acc[7] };
    float* obase = out + (size_t)row * TOKEN_DIM + (size_t)t * 8;
    __builtin_nontemporal_store(lo, reinterpret_cast<f32x4*>(obase));
    __builtin_nontemporal_store(hi, reinterpret_cast<f32x4*>(obase) + 1);
}

// ---- fallback: pure fp32 gather (if d_ws too small) ----
__global__ __launch_bounds__(256) void multi_embed_f32_kernel(
    const int* __restrict__ x1, const int* __restrict__ x2,
    const float* __restrict__ weight, float* __restrict__ out,
    int n1, int n2)
{
    const int row = blockIdx.x;
    const int c4  = threadIdx.x;
    f32x4 acc = (f32x4)(0.f);
    if (row < n1) {
        const int* idx = x1 + (size_t)row * 8;
        #pragma unroll
        for (int l = 0; l < 8; ++l) {
            const int tok = idx[l];
            acc += reinterpret_cast<const f32x4*>(
                weight + ((size_t)l * N_TOKENS + (size_t)tok) * TOKEN_DIM)[c4];
        }
    } else {
        const int r = row - n1;
        if (r >= n2) return;
        const int* idx = x2 + (size_t)r * 4;
        #pragma unroll
        for (int l = 0; l < 4; ++l) {
            const int tok = idx[l];
            acc += reinterpret_cast<const f32x4*>(
                weight + ((size_t)l * N_TOKENS + (size_t)tok) * TOKEN_DIM)[c4];
        }
    }
    f32x4* o = reinterpret_cast<f32x4*>(out + (size_t)row * TOKEN_DIM);
    __builtin_nontemporal_store(acc, &o[c4]);
}

extern "C" void kernel_launch(void* const* d_in, const int* in_sizes, int n_in,
                              void* d_out, int out_size, void* d_ws, size_t ws_size,
                              hipStream_t stream) {
    const int*   x1 = (const int*)d_in[0];
    const int*   x2 = (const int*)d_in[1];
    const float* w  = (const float*)d_in[2];
    float*       o  = (float*)d_out;

    const int n1 = in_sizes[0] / 8;   // 8192
    const int n2 = in_sizes[1] / 4;   // 8192

    const size_t wb_bytes = (size_t)N_LEVELS * N_TOKENS * TOKEN_DIM * sizeof(unsigned short);

    if (ws_size >= wb_bytes) {
        unsigned short* wb = (unsigned short*)d_ws;
        const int n4 = (N_LEVELS * N_TOKENS * TOKEN_DIM) / 4;   // 2M float4s
        convert_w_kernel<<<2048, 256, 0, stream>>>(w, wb, n4);

        const int rows = n1 + n2;
        if ((n1 % ROWS_PER_BLOCK) == 0 && (rows % ROWS_PER_BLOCK) == 0) {
            const int blocks = 8 * (rows / ROWS_PER_BLOCK);   // 2048
            gather_sliced_kernel<<<blocks, 256, 0, stream>>>(x1, x2, wb, o, n1, n2);
        } else {
            gather_bf16_kernel<<<rows, 128, 0, stream>>>(x1, x2, wb, o, n1, n2);
        }
    } else {
        multi_embed_f32_kernel<<<n1 + n2, 256, 0, stream>>>(x1, x2, w, o, n1, n2);
    }
}

// Round 5
// 34.909 us; speedup vs baseline: 1.7888x; 1.1253x over previous
//
#include <hip/hip_runtime.h>
#include <hip/hip_bf16.h>

// MultiEmbedding: out1[r,:] = sum_{l<8} W[l, x1[r,l], :]
//                 out2[r,:] = sum_{l<4} W[l, x2[r,l], :]
// W: [8, 1024, 1024] fp32, x1: [8192,8] i32, x2: [8192,4] i32.
//
// Pass 1 (convert_pack): W -> bf16 into d_ws, PACKED PER COLUMN-SLICE:
//   wb[slice][level][token][128 cols], slice = blockIdx%8 -> XCD slice.
//   Normal stores (not NT) so each XCD's 2 MiB slice stays resident in the
//   same XCD's 4 MiB L2 that the gather pass will read it from.
// Pass 2 (gather): slice = blockIdx%8 (same XCD mapping). Reads are L2 hits
//   on a contiguous 2 MiB working set (uniform L2 set/channel usage, unlike
//   the 2KiB-periodic interleaved layout). Output written NT (never re-read).

#define TOKEN_DIM 1024
#define N_TOKENS  1024
#define N_LEVELS  8

#define SLICES      8
#define SLICE_COLS  128                       // TOKEN_DIM / SLICES
#define SLICE_ROWS  (N_LEVELS * N_TOKENS)     // 8192 (l,token) rows
#define SLICE_ELEMS ((size_t)SLICE_ROWS * SLICE_COLS)  // 1M bf16 = 2 MiB

#define ROWS_PER_BLOCK 64
#define ROWS_PER_ITER  16    // 256 threads / 16 col-groups

typedef float          f32x4 __attribute__((ext_vector_type(4)));
typedef unsigned short u16x4 __attribute__((ext_vector_type(4)));
typedef unsigned short u16x8 __attribute__((ext_vector_type(8)));

__device__ __forceinline__ unsigned short f2bf_rne(float f) {
    unsigned int u = __float_as_uint(f);
    u += 0x7fffu + ((u >> 16) & 1u);     // round-to-nearest-even
    return (unsigned short)(u >> 16);
}
__device__ __forceinline__ float bf2f(unsigned short u) {
    return __uint_as_float(((unsigned int)u) << 16);
}

// ---- pass 1: fp32 -> bf16, packed per slice, L2-warm (normal stores) ----
// blockIdx = chunk*8 + slice; 256 chunks x 32 rows = 8192 (l,tok) rows/slice.
// Thread: lane_c = t&31 (4 cols), lrow = t>>5 (8 rows per iter).
__global__ __launch_bounds__(256) void convert_pack_kernel(
    const float* __restrict__ w, unsigned short* __restrict__ wb)
{
    const int slice  = blockIdx.x & 7;
    const int chunk  = blockIdx.x >> 3;      // 0..255
    const int lane_c = threadIdx.x & 31;
    const int lrow   = threadIdx.x >> 5;
    const int row0   = chunk * 32;

    unsigned short* ws = wb + (size_t)slice * SLICE_ELEMS;

    #pragma unroll
    for (int it = 0; it < 4; ++it) {
        const int row = row0 + it * 8 + lrow;          // (l*1024 + tok)
        const f32x4 v = *reinterpret_cast<const f32x4*>(
            w + (size_t)row * TOKEN_DIM + slice * SLICE_COLS + lane_c * 4);
        u16x4 o;
        o.x = f2bf_rne(v.x); o.y = f2bf_rne(v.y);
        o.z = f2bf_rne(v.z); o.w = f2bf_rne(v.w);
        *reinterpret_cast<u16x4*>(
            ws + (size_t)row * SLICE_COLS + lane_c * 4) = o;   // normal store
    }
}

// ---- pass 2: packed, column-sliced gather ----
// blockIdx = chunk*8 + slice. Thread: g = t&15 (8 cols), lr = t>>4 (16 rows).
__global__ __launch_bounds__(256) void gather_packed_kernel(
    const int* __restrict__ x1, const int* __restrict__ x2,
    const unsigned short* __restrict__ wb, float* __restrict__ out,
    int n1, int n2)
{
    const int slice = blockIdx.x & 7;
    const int chunk = blockIdx.x >> 3;
    const int row0  = chunk * ROWS_PER_BLOCK;
    const int g     = threadIdx.x & 15;
    const int lr    = threadIdx.x >> 4;

    const unsigned short* ws = wb + (size_t)slice * SLICE_ELEMS;
    const int col = slice * SLICE_COLS + g * 8;

    const bool is_x1 = (row0 < n1);   // chunks never straddle (n1 % 64 == 0)

    #pragma unroll
    for (int it = 0; it < ROWS_PER_BLOCK / ROWS_PER_ITER; ++it) {
        const int row = row0 + it * ROWS_PER_ITER + lr;

        float acc[8];
        #pragma unroll
        for (int j = 0; j < 8; ++j) acc[j] = 0.f;

        if (is_x1) {
            const int* idx = x1 + (size_t)row * 8;
            u16x8 v[8];
            #pragma unroll
            for (int l = 0; l < 8; ++l) {
                const int tok = idx[l];
                v[l] = *reinterpret_cast<const u16x8*>(
                    ws + ((size_t)l * N_TOKENS + (size_t)tok) * SLICE_COLS + g * 8);
            }
            #pragma unroll
            for (int l = 0; l < 8; ++l)
                #pragma unroll
                for (int j = 0; j < 8; ++j) acc[j] += bf2f(v[l][j]);
        } else {
            const int r = row - n1;
            const int* idx = x2 + (size_t)r * 4;
            u16x8 v[4];
            #pragma unroll
            for (int l = 0; l < 4; ++l) {
                const int tok = idx[l];
                v[l] = *reinterpret_cast<const u16x8*>(
                    ws + ((size_t)l * N_TOKENS + (size_t)tok) * SLICE_COLS + g * 8);
            }
            #pragma unroll
            for (int l = 0; l < 4; ++l)
                #pragma unroll
                for (int j = 0; j < 8; ++j) acc[j] += bf2f(v[l][j]);
        }

        f32x4 lo = { acc[0], acc[1], acc[2], acc[3] };
        f32x4 hi = { acc[4], acc[5], acc[6], acc[7] };
        float* obase = out + (size_t)row * TOKEN_DIM + col;
        __builtin_nontemporal_store(lo, reinterpret_cast<f32x4*>(obase));
        __builtin_nontemporal_store(hi, reinterpret_cast<f32x4*>(obase) + 1);
    }
}

// ---- fallback: pure fp32 gather (if d_ws too small or odd shapes) ----
__global__ __launch_bounds__(256) void multi_embed_f32_kernel(
    const int* __restrict__ x1, const int* __restrict__ x2,
    const float* __restrict__ weight, float* __restrict__ out,
    int n1, int n2)
{
    const int row = blockIdx.x;
    const int c4  = threadIdx.x;
    f32x4 acc = (f32x4)(0.f);
    if (row < n1) {
        const int* idx = x1 + (size_t)row * 8;
        #pragma unroll
        for (int l = 0; l < 8; ++l) {
            const int tok = idx[l];
            acc += reinterpret_cast<const f32x4*>(
                weight + ((size_t)l * N_TOKENS + (size_t)tok) * TOKEN_DIM)[c4];
        }
    } else {
        const int r = row - n1;
        if (r >= n2) return;
        const int* idx = x2 + (size_t)r * 4;
        #pragma unroll
        for (int l = 0; l < 4; ++l) {
            const int tok = idx[l];
            acc += reinterpret_cast<const f32x4*>(
                weight + ((size_t)l * N_TOKENS + (size_t)tok) * TOKEN_DIM)[c4];
        }
    }
    f32x4* o = reinterpret_cast<f32x4*>(out + (size_t)row * TOKEN_DIM);
    __builtin_nontemporal_store(acc, &o[c4]);
}

extern "C" void kernel_launch(void* const* d_in, const int* in_sizes, int n_in,
                              void* d_out, int out_size, void* d_ws, size_t ws_size,
                              hipStream_t stream) {
    const int*   x1 = (const int*)d_in[0];
    const int*   x2 = (const int*)d_in[1];
    const float* w  = (const float*)d_in[2];
    float*       o  = (float*)d_out;

    const int n1 = in_sizes[0] / 8;   // 8192
    const int n2 = in_sizes[1] / 4;   // 8192
    const int rows = n1 + n2;

    const size_t wb_bytes = (size_t)SLICES * SLICE_ELEMS * sizeof(unsigned short);

    if (ws_size >= wb_bytes && (n1 % ROWS_PER_BLOCK) == 0 && (rows % ROWS_PER_BLOCK) == 0) {
        unsigned short* wb = (unsigned short*)d_ws;
        convert_pack_kernel<<<256 * SLICES, 256, 0, stream>>>(w, wb);
        gather_packed_kernel<<<(rows / ROWS_PER_BLOCK) * SLICES, 256, 0, stream>>>(
            x1, x2, wb, o, n1, n2);
    } else {
        multi_embed_f32_kernel<<<rows, 256, 0, stream>>>(x1, x2, w, o, n1, n2);
    }
}